// Round 10
// baseline (353.221 us; speedup 1.0000x reference)
//
#include <hip/hip_runtime.h>
#include <hip/hip_bf16.h>

// FeatureAttention: B=4,T=2048,D=2048,H=16,HO=128
// Gram path: scores_h = Wq_h^T (X^T X) Wk_h  (q,k never materialized).
// ctx+out fused: out = v @ Mstack^T + alibi (x) colsum(Wp) + bp,
//   Mstack[b][n][hg] = sum_f wts[b,h,f,g] Wp[hf,n]  (softmax rows sum to 1).

#define Tt 2048
#define Dd 2048
#define Mm 8192   // B*T

typedef __attribute__((ext_vector_type(4))) float f32x4;
typedef __attribute__((ext_vector_type(8))) short s16x8;
static_assert(sizeof(s16x8) == 16, "frag size");

typedef const __attribute__((address_space(1))) void* gptr_t;
typedef __attribute__((address_space(3))) void* lptr_t;

__device__ __forceinline__ float bf2f(ushort u) {
    union { unsigned int i; float f; } c; c.i = ((unsigned int)u) << 16; return c.f;
}
__device__ __forceinline__ ushort f2bf(float f) {
    union { float f; unsigned int i; } c; c.f = f;
    return (ushort)((c.i + 0x7FFFu + ((c.i >> 16) & 1u)) >> 16);
}
__device__ __forceinline__ void gload16(const void* g, void* l) {
    __builtin_amdgcn_global_load_lds((gptr_t)g, (lptr_t)l, 16, 0, 0);
}
__device__ __forceinline__ s16x8 ldfrag(const char* p) { return *(const s16x8*)p; }

#define MFMA_BF16(d, a, b) \
    d = __builtin_amdgcn_mfma_f32_16x16x32_bf16((a), (b), (d), 0, 0, 0)

// ---------------- fused convert + transpose: x -> xb [b*t][d], xT [b][d][t] ----------------

__global__ __launch_bounds__(256) void convxT_kernel(const float* __restrict__ x,
        ushort* __restrict__ xb, ushort* __restrict__ xT) {
    __shared__ float tile[64][65];
    const int b = blockIdx.z;
    const int t0 = blockIdx.y * 64, d0 = blockIdx.x * 64;
    const int r4 = threadIdx.x >> 6, c = threadIdx.x & 63;
#pragma unroll
    for (int i = 0; i < 16; i++) {
        const int row = i * 4 + r4;
        const size_t g = ((size_t)b * Tt + t0 + row) * Dd + d0 + c;
        const float val = x[g];
        xb[g] = f2bf(val);
        tile[row][c] = val;
    }
    __syncthreads();
#pragma unroll
    for (int i = 0; i < 16; i++) {
        const int row = i * 4 + r4;   // d-row
        xT[(size_t)b * ((size_t)Dd * Tt) + (size_t)(d0 + row) * Tt + t0 + c] =
            f2bf(tile[c][row]);
    }
}

// W [K=d_in][N=d_out] fp32 -> Wt [N][K] bf16.  For z==3 (Wp), also accumulate
// column sums into S (S zeroed via hipMemsetAsync before this launch).

__global__ __launch_bounds__(256) void transw_kernel(const float* __restrict__ W0,
        const float* __restrict__ W1, const float* __restrict__ W2,
        const float* __restrict__ W3, ushort* __restrict__ Wt,
        float* __restrict__ S) {
    __shared__ float tile[64][65];
    const int z = blockIdx.z;
    const float* W = (z == 0) ? W0 : (z == 1) ? W1 : (z == 2) ? W2 : W3;
    ushort* dst = Wt + (size_t)z * ((size_t)Dd * Dd);
    const int n0 = blockIdx.x * 64, k0 = blockIdx.y * 64;
    const int r4 = threadIdx.x >> 6, c = threadIdx.x & 63;
#pragma unroll
    for (int i = 0; i < 16; i++) {
        const int row = i * 4 + r4;
        tile[row][c] = W[(size_t)(k0 + row) * Dd + n0 + c];
    }
    __syncthreads();
#pragma unroll
    for (int i = 0; i < 16; i++) {
        const int row = i * 4 + r4;
        dst[(size_t)(n0 + row) * Dd + k0 + c] = f2bf(tile[c][row]);
    }
    if (z == 3) {
        float partial = 0.f;
#pragma unroll
        for (int i = 0; i < 16; i++) partial += tile[r4 * 16 + i][c];
        atomicAdd(&S[n0 + c], partial);
    }
}

// ---------------- 256x256 8-phase GEMM: C[M,N] = A[M,K] * Bt[N,K]^T ----------------
// bf16 in, fp32 acc. MODE 0: C bf16. MODE 2: C fp32 + alibi[row]*S[col] + bias[col].
// z-batched via astride/bstride/cstride. R7-VERBATIM schedule (verified passing):
// 8-phase / 2-K-tile loop, one half-tile staged per phase, pre-barrier lgkm(8)
// on 12-read phases, counted vmcnt(4) at P3/P7. NT must be even.

__device__ __forceinline__ void stage_half(char* ldsRegion, const ushort* gRegion,
                                           int ld, int half, int tid) {
#pragma unroll
    for (int j = 0; j < 2; j++) {
        const int Pb = half * 16384 + j * 8192 + (tid >> 6) * 1024;  // wave-uniform
        const int P = Pb + (tid & 63) * 16;                          // lane slot
        const int row = P >> 7;
        const int colb = (P ^ ((row & 7) << 4)) & 127;               // logical col bytes
        gload16(gRegion + (size_t)row * ld + (colb >> 1), ldsRegion + Pb);
    }
}

template <int MODE>
__global__ __launch_bounds__(512, 2) void gemm256_kernel(
        const ushort* __restrict__ A, const ushort* __restrict__ Bt,
        void* __restrict__ Cv, const float* __restrict__ bias,
        const float* __restrict__ S,
        int Kdim, int lda, int ldb, int ldc,
        size_t astride, size_t bstride, size_t cstride) {
    extern __shared__ char lds[];   // 2 x (A 32768 + B 32768) = 131072 B

    const int tid = threadIdx.x;
    const int lane = tid & 63;
    const int w = tid >> 6;
    const int wr = w >> 2, wc = w & 3;        // 2 x 4 waves
    const int fr = lane & 15, fq = lane >> 4;

    // XCD-aware bijective swizzle (gridDim.x % 8 == 0)
    const int bid = blockIdx.x;
    const int cpx = (int)gridDim.x >> 3;
    const int wg = (bid & 7) * cpx + (bid >> 3);
    const int m0 = (wg >> 3) * 256;           // 8 n-tiles (N = 2048)
    const int n0 = (wg & 7) * 256;

    const ushort* Ag = A + (size_t)blockIdx.z * astride + (size_t)m0 * lda;
    const ushort* Bg = Bt + (size_t)blockIdx.z * bstride + (size_t)n0 * ldb;
    const int NT = Kdim >> 6;                 // even

    // per-thread invariant LDS read offsets (swizzle: row&7 == fr&7)
    const int aoff = wr * 16384 + fr * 128;
    const int boff = wc * 8192 + fr * 128;
    const int xo = (fr & 7) << 4;
    const int cp0 = (fq * 16) ^ xo;           // k-sub 0
    const int cp1 = (64 + fq * 16) ^ xo;      // k-sub 1

    char* buf0 = lds;            // even tiles
    char* buf1 = lds + 65536;    // odd tiles
    const char* Ab0 = buf0 + aoff;
    const char* Bb0 = buf0 + 32768 + boff;
    const char* Ab1 = buf1 + aoff;
    const char* Bb1 = buf1 + 32768 + boff;

    f32x4 acc[8][4];
#pragma unroll
    for (int i = 0; i < 8; i++)
#pragma unroll
        for (int j = 0; j < 4; j++) acc[i][j] = {0.f, 0.f, 0.f, 0.f};

    s16x8 afX[4][2], afY[4][2], bf01[2][2], bf23[2][2];

    // ---- prologue: stage tiles 0 (buf0) and 1 (buf1); wait tile 0 ----
    {
        stage_half(buf0,         Ag, lda, 0, tid);
        stage_half(buf0,         Ag, lda, 1, tid);
        stage_half(buf0 + 32768, Bg, ldb, 0, tid);
        stage_half(buf0 + 32768, Bg, ldb, 1, tid);
        stage_half(buf1,         Ag + 64, lda, 0, tid);
        stage_half(buf1,         Ag + 64, lda, 1, tid);
        stage_half(buf1 + 32768, Bg + 64, ldb, 0, tid);
        stage_half(buf1 + 32768, Bg + 64, ldb, 1, tid);
        __builtin_amdgcn_sched_barrier(0);
        asm volatile("s_waitcnt vmcnt(8)" ::: "memory");
        __builtin_amdgcn_s_barrier();
    }

    const int NI = NT >> 1;
    for (int j = 0; j < NI; ++j) {
        const int e = 2 * j;
        const bool sAo = (j > 0);             // stage A(e+1) at P0/P1
        const bool sE2 = (e + 2 < NT);        // stage tile e+2 at P2..P5
        const bool sO2 = (e + 3 < NT);        // stage tile e+3 at P6/P7
        const ushort* AgO  = Ag + (size_t)(e + 1) * 64;
        const ushort* AgE2 = Ag + (size_t)(e + 2) * 64;
        const ushort* BgE2 = Bg + (size_t)(e + 2) * 64;
        const ushort* BgO2 = Bg + (size_t)(e + 3) * 64;

        // ===== P0: reads afX(e)+bf01(e) [12]; stage A-lo(e+1); lgkm(8); bar; Q0 =====
#pragma unroll
        for (int m = 0; m < 4; m++) {
            afX[m][0] = ldfrag(Ab0 + m * 2048 + cp0);
            afX[m][1] = ldfrag(Ab0 + m * 2048 + cp1);
        }
#pragma unroll
        for (int n = 0; n < 2; n++) {
            bf01[n][0] = ldfrag(Bb0 + n * 2048 + cp0);
            bf01[n][1] = ldfrag(Bb0 + n * 2048 + cp1);
        }
        if (sAo) stage_half(buf1, AgO, lda, 0, tid);
        __builtin_amdgcn_sched_barrier(0);
        asm volatile("s_waitcnt lgkmcnt(8)" ::: "memory");
        __builtin_amdgcn_s_barrier();
        asm volatile("s_waitcnt lgkmcnt(0)" ::: "memory");
        __builtin_amdgcn_sched_barrier(0);
        __builtin_amdgcn_s_setprio(1);
#pragma unroll
        for (int k = 0; k < 2; k++)
#pragma unroll
            for (int m = 0; m < 4; m++)
#pragma unroll
                for (int n = 0; n < 2; n++) MFMA_BF16(acc[m][n], afX[m][k], bf01[n][k]);
        __builtin_amdgcn_s_setprio(0);
        __builtin_amdgcn_s_barrier();

        // ===== P1: reads bf23(e) [4]; stage A-hi(e+1); bar; Q1 =====
#pragma unroll
        for (int n = 0; n < 2; n++) {
            bf23[n][0] = ldfrag(Bb0 + (n + 2) * 2048 + cp0);
            bf23[n][1] = ldfrag(Bb0 + (n + 2) * 2048 + cp1);
        }
        if (sAo) stage_half(buf1, AgO, lda, 1, tid);
        __builtin_amdgcn_sched_barrier(0);
        __builtin_amdgcn_s_barrier();
        asm volatile("s_waitcnt lgkmcnt(0)" ::: "memory");
        __builtin_amdgcn_sched_barrier(0);
        __builtin_amdgcn_s_setprio(1);
#pragma unroll
        for (int k = 0; k < 2; k++)
#pragma unroll
            for (int m = 0; m < 4; m++)
#pragma unroll
                for (int n = 0; n < 2; n++) MFMA_BF16(acc[m][n + 2], afX[m][k], bf23[n][k]);
        __builtin_amdgcn_s_setprio(0);
        __builtin_amdgcn_s_barrier();

        // ===== P2: reads afY(e) [8]; stage B-lo(e+2) (buf0-B free after P1); Q2 =====
#pragma unroll
        for (int m = 0; m < 4; m++) {
            afY[m][0] = ldfrag(Ab0 + (m + 4) * 2048 + cp0);
            afY[m][1] = ldfrag(Ab0 + (m + 4) * 2048 + cp1);
        }
        if (sE2) stage_half(buf0 + 32768, BgE2, ldb, 0, tid);
        __builtin_amdgcn_sched_barrier(0);
        __builtin_amdgcn_s_barrier();
        asm volatile("s_waitcnt lgkmcnt(0)" ::: "memory");
        __builtin_amdgcn_sched_barrier(0);
        __builtin_amdgcn_s_setprio(1);
#pragma unroll
        for (int k = 0; k < 2; k++)
#pragma unroll
            for (int m = 0; m < 4; m++)
#pragma unroll
                for (int n = 0; n < 2; n++) MFMA_BF16(acc[m + 4][n], afY[m][k], bf01[n][k]);
        __builtin_amdgcn_s_setprio(0);
        __builtin_amdgcn_s_barrier();

        // ===== P3: stage B-hi(e+2); Q3; vmcnt(4): A(e+1) landed for P4 =====
        if (sE2) stage_half(buf0 + 32768, BgE2, ldb, 1, tid);
        __builtin_amdgcn_sched_barrier(0);
        __builtin_amdgcn_s_setprio(1);
#pragma unroll
        for (int k = 0; k < 2; k++)
#pragma unroll
            for (int m = 0; m < 4; m++)
#pragma unroll
                for (int n = 0; n < 2; n++) MFMA_BF16(acc[m + 4][n + 2], afY[m][k], bf23[n][k]);
        __builtin_amdgcn_s_setprio(0);
        __builtin_amdgcn_sched_barrier(0);
        if (sE2) asm volatile("s_waitcnt vmcnt(4)" ::: "memory");
        else     asm volatile("s_waitcnt vmcnt(0)" ::: "memory");
        __builtin_amdgcn_s_barrier();

        // ===== P4: reads afX(o)+bf01(o) [12]; stage A-lo(e+2) (buf0-A free after P2) =====
#pragma unroll
        for (int m = 0; m < 4; m++) {
            afX[m][0] = ldfrag(Ab1 + m * 2048 + cp0);
            afX[m][1] = ldfrag(Ab1 + m * 2048 + cp1);
        }
#pragma unroll
        for (int n = 0; n < 2; n++) {
            bf01[n][0] = ldfrag(Bb1 + n * 2048 + cp0);
            bf01[n][1] = ldfrag(Bb1 + n * 2048 + cp1);
        }
        if (sE2) stage_half(buf0, AgE2, lda, 0, tid);
        __builtin_amdgcn_sched_barrier(0);
        asm volatile("s_waitcnt lgkmcnt(8)" ::: "memory");
        __builtin_amdgcn_s_barrier();
        asm volatile("s_waitcnt lgkmcnt(0)" ::: "memory");
        __builtin_amdgcn_sched_barrier(0);
        __builtin_amdgcn_s_setprio(1);
#pragma unroll
        for (int k = 0; k < 2; k++)
#pragma unroll
            for (int m = 0; m < 4; m++)
#pragma unroll
                for (int n = 0; n < 2; n++) MFMA_BF16(acc[m][n], afX[m][k], bf01[n][k]);
        __builtin_amdgcn_s_setprio(0);
        __builtin_amdgcn_s_barrier();

        // ===== P5: reads bf23(o) [4]; stage A-hi(e+2); Q1 =====
#pragma unroll
        for (int n = 0; n < 2; n++) {
            bf23[n][0] = ldfrag(Bb1 + (n + 2) * 2048 + cp0);
            bf23[n][1] = ldfrag(Bb1 + (n + 2) * 2048 + cp1);
        }
        if (sE2) stage_half(buf0, AgE2, lda, 1, tid);
        __builtin_amdgcn_sched_barrier(0);
        __builtin_amdgcn_s_barrier();
        asm volatile("s_waitcnt lgkmcnt(0)" ::: "memory");
        __builtin_amdgcn_sched_barrier(0);
        __builtin_amdgcn_s_setprio(1);
#pragma unroll
        for (int k = 0; k < 2; k++)
#pragma unroll
            for (int m = 0; m < 4; m++)
#pragma unroll
                for (int n = 0; n < 2; n++) MFMA_BF16(acc[m][n + 2], afX[m][k], bf23[n][k]);
        __builtin_amdgcn_s_setprio(0);
        __builtin_amdgcn_s_barrier();

        // ===== P6: reads afY(o) [8]; stage B-lo(e+3) (buf1-B free after P5); Q2 =====
#pragma unroll
        for (int m = 0; m < 4; m++) {
            afY[m][0] = ldfrag(Ab1 + (m + 4) * 2048 + cp0);
            afY[m][1] = ldfrag(Ab1 + (m + 4) * 2048 + cp1);
        }
        if (sO2) stage_half(buf1 + 32768, BgO2, ldb, 0, tid);
        __builtin_amdgcn_sched_barrier(0);
        __builtin_amdgcn_s_barrier();
        asm volatile("s_waitcnt lgkmcnt(0)" ::: "memory");
        __builtin_amdgcn_sched_barrier(0);
        __builtin_amdgcn_s_setprio(1);
#pragma unroll
        for (int k = 0; k < 2; k++)
#pragma unroll
            for (int m = 0; m < 4; m++)
#pragma unroll
                for (int n = 0; n < 2; n++) MFMA_BF16(acc[m + 4][n], afY[m][k], bf01[n][k]);
        __builtin_amdgcn_s_setprio(0);
        __builtin_amdgcn_s_barrier();

        // ===== P7: stage B-hi(e+3); Q3; vmcnt(4): tile e+2 landed for next P0 =====
        if (sO2) stage_half(buf1 + 32768, BgO2, ldb, 1, tid);
        __builtin_amdgcn_sched_barrier(0);
        __builtin_amdgcn_s_setprio(1);
#pragma unroll
        for (int k = 0; k < 2; k++)
#pragma unroll
            for (int m = 0; m < 4; m++)
#pragma unroll
                for (int n = 0; n < 2; n++) MFMA_BF16(acc[m + 4][n + 2], afY[m][k], bf23[n][k]);
        __builtin_amdgcn_s_setprio(0);
        __builtin_amdgcn_sched_barrier(0);
        if (sO2) asm volatile("s_waitcnt vmcnt(4)" ::: "memory");
        else     asm volatile("s_waitcnt vmcnt(0)" ::: "memory");
        __builtin_amdgcn_s_barrier();
    }

    if (MODE == 2) {
        float* C = (float*)Cv + (size_t)blockIdx.z * cstride;
#pragma unroll
        for (int mi = 0; mi < 8; mi++)
#pragma unroll
            for (int ni = 0; ni < 4; ni++)
#pragma unroll
                for (int r = 0; r < 4; r++) {
                    const int row = m0 + wr * 128 + mi * 16 + fq * 4 + r;
                    const int col = n0 + wc * 64 + ni * 16 + fr;
                    const float alibi = 1.0f / (float)(Tt - row);
                    C[(size_t)row * ldc + col] =
                        acc[mi][ni][r] + alibi * S[col] + bias[col];
                }
    } else {
        ushort* C = (ushort*)Cv + (size_t)blockIdx.z * cstride;
#pragma unroll
        for (int mi = 0; mi < 8; mi++)
#pragma unroll
            for (int ni = 0; ni < 4; ni++)
#pragma unroll
                for (int r = 0; r < 4; r++) {
                    const int row = m0 + wr * 128 + mi * 16 + fq * 4 + r;
                    const int col = n0 + wc * 64 + ni * 16 + fr;
                    C[(size_t)row * ldc + col] = f2bf(acc[mi][ni][r]);
                }
    }
}

// ---------------- 128x128 GEMM ----------------
// MODE 3: scores GEMM, z = s*64 + bh, split-K=4 over d; C fp32 -> part.
// MODE 4: Mstack builder, z = b*16 + h: C[n][h*128+g] = sum_f Wt_p[n][hf] wtsT[g][f].

template <int MODE>
__global__ __launch_bounds__(256, 2) void gemm_kernel(
        const ushort* __restrict__ A, const ushort* __restrict__ Bt,
        void* __restrict__ Cv,
        int Kdim, int lda, int ldb, int ldc) {
    __shared__ ushort lsA[128 * 32];
    __shared__ ushort lsB[128 * 32];

    const int tid = threadIdx.x;
    const int w = tid >> 6, lane = tid & 63;
    const int m0 = blockIdx.y * 128;
    const int n0 = blockIdx.x * 128;

    const ushort* Ab = A;
    const ushort* Bb = Bt;
    size_t coff = 0;
    if (MODE == 3) {
        const int z = blockIdx.z, s = z >> 6, bh = z & 63;
        const int b = bh >> 4, h = bh & 15;
        Ab += (size_t)h * 128 * Dd + (size_t)s * 512;
        Bb += (size_t)b * ((size_t)Dd * Dd) + (size_t)h * 128 * Dd + (size_t)s * 512;
        coff = (size_t)s * (64 * 16384) + (size_t)bh * 16384;
    }
    if (MODE == 4) {
        const int z = blockIdx.z, b = z >> 4, h = z & 15;
        Ab += (size_t)h * 128;                    // k-offset into Wt_p
        Bb += (size_t)z * 16384;                  // wtsT block [g][f]
        coff = (size_t)b * ((size_t)Dd * Dd) + (size_t)h * 128;
    }

    const int sr = lane >> 2;
    const int sc = (lane & 3) * 8;
    const int c0 = w, c1 = w + 4;
    const int rA0 = c0 * 16 + sr, rA1 = c1 * 16 + sr;

    const int fr = lane & 15, fq = lane >> 4;
    const int wr = (w >> 1) * 64, wc = (w & 1) * 64;

    f32x4 acc[4][4];
#pragma unroll
    for (int i = 0; i < 4; i++)
#pragma unroll
        for (int j = 0; j < 4; j++) acc[i][j] = {0.f, 0.f, 0.f, 0.f};

    for (int kt = 0; kt < Kdim; kt += 32) {
        gload16(Ab + (size_t)(m0 + rA0) * lda + kt + sc, lsA + c0 * 512);
        gload16(Ab + (size_t)(m0 + rA1) * lda + kt + sc, lsA + c1 * 512);
        gload16(Bb + (size_t)(n0 + rA0) * ldb + kt + sc, lsB + c0 * 512);
        gload16(Bb + (size_t)(n0 + rA1) * ldb + kt + sc, lsB + c1 * 512);
        __syncthreads();

        s16x8 afrag[4], bfrag[4];
#pragma unroll
        for (int i = 0; i < 4; i++)
            afrag[i] = *(const s16x8*)(lsA + (wr + i * 16 + fr) * 32 + fq * 8);
#pragma unroll
        for (int j = 0; j < 4; j++)
            bfrag[j] = *(const s16x8*)(lsB + (wc + j * 16 + fr) * 32 + fq * 8);
#pragma unroll
        for (int i = 0; i < 4; i++)
#pragma unroll
            for (int j = 0; j < 4; j++)
                MFMA_BF16(acc[i][j], afrag[i], bfrag[j]);
        __syncthreads();
    }

    if (MODE == 3) {
        float* C = (float*)Cv + coff;
#pragma unroll
        for (int i = 0; i < 4; i++)
#pragma unroll
            for (int j = 0; j < 4; j++)
#pragma unroll
                for (int r = 0; r < 4; r++) {
                    const int row = m0 + wr + i * 16 + fq * 4 + r;
                    const int col = n0 + wc + j * 16 + fr;
                    C[(size_t)row * ldc + col] = acc[i][j][r];
                }
    } else {
        ushort* C = (ushort*)Cv + coff;
#pragma unroll
        for (int i = 0; i < 4; i++)
#pragma unroll
            for (int j = 0; j < 4; j++)
#pragma unroll
                for (int r = 0; r < 4; r++) {
                    const int row = m0 + wr + i * 16 + fq * 4 + r;
                    const int col = n0 + wc + j * 16 + fr;
                    C[(size_t)row * ldc + col] = f2bf(acc[i][j][r]);
                }
    }
}

// ---------------- softmax over g -> TRANSPOSED weights wtsT[bh][g][f] bf16 ----------------

__global__ __launch_bounds__(256) void softmax_kernel(const float* __restrict__ part,
                                                      ushort* __restrict__ wtsT) {
    const int tid = threadIdx.x;
    const int wv = tid >> 6, lane = tid & 63;
    const int row = blockIdx.x * 4 + wv;          // row = bh*128 + f
    const float* p = part + (size_t)row * 128 + lane * 2;
    float v0 = 0.f, v1 = 0.f;
#pragma unroll
    for (int s = 0; s < 4; s++) {
        const float2 t = *(const float2*)(p + (size_t)s * 1048576);
        v0 += t.x; v1 += t.y;
    }
    const float sc = 0.088388347648318447f;  // 1/sqrt(128)
    v0 *= sc; v1 *= sc;
    float m = fmaxf(v0, v1);
#pragma unroll
    for (int off = 32; off > 0; off >>= 1) m = fmaxf(m, __shfl_xor(m, off));
    const float e0 = __expf(v0 - m), e1 = __expf(v1 - m);
    float smv = e0 + e1;
#pragma unroll
    for (int off = 32; off > 0; off >>= 1) smv += __shfl_xor(smv, off);
    const float inv = 1.0f / smv;
    const int bh = row >> 7, f = row & 127;
    ushort* o = wtsT + (size_t)bh * 16384 + (size_t)(lane * 2) * 128 + f;
    o[0]   = f2bf(e0 * inv);
    o[128] = f2bf(e1 * inv);
}

// ---------------- launch ----------------

extern "C" void kernel_launch(void* const* d_in, const int* in_sizes, int n_in,
                              void* d_out, int out_size, void* d_ws, size_t ws_size,
                              hipStream_t stream) {
    const float* x  = (const float*)d_in[0];
    const float* Wq = (const float*)d_in[1];
    const float* Wk = (const float*)d_in[2];
    const float* Wv = (const float*)d_in[3];
    const float* Wp = (const float*)d_in[4];
    const float* bp = (const float*)d_in[5];
    float* out = (float*)d_out;
    char* ws = (char*)d_ws;

    // ws (MB): xb 0-32 | xT/Mt 32-64 | Wt 64-96 | G/part/wtsT 96-128 | H 128-160
    //          | v 160-192 | S 194 (OUTSIDE the G region — R8/R9 had it at 126,
    //          inside G[b=3], which the G-GEMM overwrote: the absmax-2062 bug)
    ushort* xb   = (ushort*)(ws);
    ushort* xT   = (ushort*)(ws + (32ull << 20));
    ushort* Wt   = (ushort*)(ws + (64ull << 20));
    ushort* G    = (ushort*)(ws + (96ull << 20));
    ushort* Hb   = (ushort*)(ws + (128ull << 20));
    ushort* v    = (ushort*)(ws + (160ull << 20));
    float*  part = (float*) (ws + (96ull << 20));   // overlays G[b0,b1] (dead after H)
    ushort* wtsT = (ushort*)(ws + (112ull << 20));  // overlays G[b2] (dead after H)
    float*  S    = (float*) (ws + (194ull << 20));  // safe: beyond v region
    ushort* Mt   = xT;                              // xT dead after G

    const size_t WSZ = (size_t)Dd * Dd;  // 4M elements
    const size_t TD  = (size_t)Tt * Dd;

    static_cast<void>(hipFuncSetAttribute((const void*)gemm256_kernel<0>,
        hipFuncAttributeMaxDynamicSharedMemorySize, 131072));
    static_cast<void>(hipFuncSetAttribute((const void*)gemm256_kernel<2>,
        hipFuncAttributeMaxDynamicSharedMemorySize, 131072));

    static_cast<void>(hipMemsetAsync(S, 0, Dd * sizeof(float), stream));
    convxT_kernel<<<dim3(32, 32, 4), 256, 0, stream>>>(x, xb, xT);
    transw_kernel<<<dim3(32, 32, 4), 256, 0, stream>>>(Wq, Wk, Wv, Wp, Wt, S);

    // G_b = X_b^T X_b : A = Bt = xT_b [d][t]
    gemm256_kernel<0><<<dim3(64, 1, 4), 512, 131072, stream>>>(
        xT, xT, G, nullptr, nullptr, 2048, 2048, 2048, 2048, WSZ, WSZ, WSZ);

    // H_b = Wk^T G_b : A = Wt_k, Bt = G_b
    gemm256_kernel<0><<<dim3(64, 1, 4), 512, 131072, stream>>>(
        Wt + WSZ, G, Hb, nullptr, nullptr, 2048, 2048, 2048, 2048, 0, WSZ, WSZ);

    // v = X Wv
    gemm256_kernel<0><<<dim3(256, 1, 1), 512, 131072, stream>>>(
        xb, Wt + 2 * WSZ, v, nullptr, nullptr, 2048, 2048, 2048, 2048, 0, 0, 0);

    // scores: part[s][bh][f][g] = sum_{d in slice s} Wt_q[hf][d] * H_b[hg][d]
    gemm_kernel<3><<<dim3(1, 1, 256), 256, 0, stream>>>(
        Wt, Hb, part, 512, 2048, 2048, 128);

    softmax_kernel<<<2048, 256, 0, stream>>>(part, wtsT);

    // Mt[b][n][h*128+g] = sum_f Wt_p[n][hf] * wtsT[bh][g][f]
    gemm_kernel<4><<<dim3(1, 16, 64), 256, 0, stream>>>(
        Wt + 3 * WSZ, wtsT, Mt, 128, 2048, 128, 2048);

    // out_b = v_b @ Mt_b^T + alibi (x) S + bp   (fp32 out)
    gemm256_kernel<2><<<dim3(64, 1, 4), 512, 131072, stream>>>(
        v, Mt, out, bp, S, 2048, 2048, 2048, 2048, TD, WSZ, TD);
}

// Round 11
// 351.398 us; speedup vs baseline: 1.0052x; 1.0052x over previous
//
#include <hip/hip_runtime.h>
#include <hip/hip_bf16.h>

// FeatureAttention: B=4,T=2048,D=2048,H=16,HO=128
// Gram path: scores_h = Wq_h^T (X^T X) Wk_h  (q,k never materialized).
// ctx+out fused: out = v @ Mstack^T + alibi (x) colsum(Wp) + bp,
//   Mstack[b][n][hg] = sum_f wts[b,h,f,g] Wp[hf,n]  (softmax rows sum to 1).

#define Tt 2048
#define Dd 2048
#define Mm 8192   // B*T

typedef __attribute__((ext_vector_type(4))) float f32x4;
typedef __attribute__((ext_vector_type(8))) short s16x8;
static_assert(sizeof(s16x8) == 16, "frag size");

typedef const __attribute__((address_space(1))) void* gptr_t;
typedef __attribute__((address_space(3))) void* lptr_t;

__device__ __forceinline__ float bf2f(ushort u) {
    union { unsigned int i; float f; } c; c.i = ((unsigned int)u) << 16; return c.f;
}
__device__ __forceinline__ ushort f2bf(float f) {
    union { float f; unsigned int i; } c; c.f = f;
    return (ushort)((c.i + 0x7FFFu + ((c.i >> 16) & 1u)) >> 16);
}
__device__ __forceinline__ void gload16(const void* g, void* l) {
    __builtin_amdgcn_global_load_lds((gptr_t)g, (lptr_t)l, 16, 0, 0);
}
__device__ __forceinline__ s16x8 ldfrag(const char* p) { return *(const s16x8*)p; }

#define MFMA_BF16(d, a, b) \
    d = __builtin_amdgcn_mfma_f32_16x16x32_bf16((a), (b), (d), 0, 0, 0)

// ---------------- fused convert + transpose: x -> xb [b*t][d], xT [b][d][t] ----------------

__global__ __launch_bounds__(256) void convxT_kernel(const float* __restrict__ x,
        ushort* __restrict__ xb, ushort* __restrict__ xT) {
    __shared__ float tile[64][65];
    const int b = blockIdx.z;
    const int t0 = blockIdx.y * 64, d0 = blockIdx.x * 64;
    const int r4 = threadIdx.x >> 6, c = threadIdx.x & 63;
#pragma unroll
    for (int i = 0; i < 16; i++) {
        const int row = i * 4 + r4;
        const size_t g = ((size_t)b * Tt + t0 + row) * Dd + d0 + c;
        const float val = x[g];
        xb[g] = f2bf(val);
        tile[row][c] = val;
    }
    __syncthreads();
#pragma unroll
    for (int i = 0; i < 16; i++) {
        const int row = i * 4 + r4;   // d-row
        xT[(size_t)b * ((size_t)Dd * Tt) + (size_t)(d0 + row) * Tt + t0 + c] =
            f2bf(tile[c][row]);
    }
}

// W [K=d_in][N=d_out] fp32 -> Wt [N][K] bf16.  For z==3 (Wp), also accumulate
// column sums into S (S zeroed via hipMemsetAsync before this launch).

__global__ __launch_bounds__(256) void transw_kernel(const float* __restrict__ W0,
        const float* __restrict__ W1, const float* __restrict__ W2,
        const float* __restrict__ W3, ushort* __restrict__ Wt,
        float* __restrict__ S) {
    __shared__ float tile[64][65];
    const int z = blockIdx.z;
    const float* W = (z == 0) ? W0 : (z == 1) ? W1 : (z == 2) ? W2 : W3;
    ushort* dst = Wt + (size_t)z * ((size_t)Dd * Dd);
    const int n0 = blockIdx.x * 64, k0 = blockIdx.y * 64;
    const int r4 = threadIdx.x >> 6, c = threadIdx.x & 63;
#pragma unroll
    for (int i = 0; i < 16; i++) {
        const int row = i * 4 + r4;
        tile[row][c] = W[(size_t)(k0 + row) * Dd + n0 + c];
    }
    __syncthreads();
#pragma unroll
    for (int i = 0; i < 16; i++) {
        const int row = i * 4 + r4;
        dst[(size_t)(n0 + row) * Dd + k0 + c] = f2bf(tile[c][row]);
    }
    if (z == 3) {
        float partial = 0.f;
#pragma unroll
        for (int i = 0; i < 16; i++) partial += tile[r4 * 16 + i][c];
        atomicAdd(&S[n0 + c], partial);
    }
}

// ---------------- 256x256 8-phase GEMM: C[M,N] = A[M,K] * Bt[N,K]^T ----------------
// bf16 in, fp32 acc. MODE 0: C bf16. MODE 2: C fp32 + alibi[row]*S[col] + bias[col].
// z-batched via astride/bstride/cstride. DEEP-PIPELINE schedule (R8, retested
// clean): stage A-hi(T1)@P0, B(T0+2)@P2/P3, A(T0+2)@P4/P5, B-lo(T1+2)@P6,
// B-hi+A-lo(T1+2)@P7. Waits: vmcnt(4)@P3 (drains T1), vmcnt(6)@P7 (drains
// T0+2, leaves 3 half-tiles in flight). NT even, NT>=2.

__device__ __forceinline__ void stage_half(char* ldsRegion, const ushort* gRegion,
                                           int ld, int half, int tid) {
#pragma unroll
    for (int j = 0; j < 2; j++) {
        const int Pb = half * 16384 + j * 8192 + (tid >> 6) * 1024;  // wave-uniform
        const int P = Pb + (tid & 63) * 16;                          // lane slot
        const int row = P >> 7;
        const int colb = (P ^ ((row & 7) << 4)) & 127;               // logical col bytes
        gload16(gRegion + (size_t)row * ld + (colb >> 1), ldsRegion + Pb);
    }
}

template <int MODE>
__global__ __launch_bounds__(512, 2) void gemm256_kernel(
        const ushort* __restrict__ A, const ushort* __restrict__ Bt,
        void* __restrict__ Cv, const float* __restrict__ bias,
        const float* __restrict__ S,
        int Kdim, int lda, int ldb, int ldc,
        size_t astride, size_t bstride, size_t cstride) {
    extern __shared__ char lds[];   // 2 x (A 32768 + B 32768) = 131072 B

    const int tid = threadIdx.x;
    const int lane = tid & 63;
    const int w = tid >> 6;
    const int wr = w >> 2, wc = w & 3;        // 2 x 4 waves
    const int fr = lane & 15, fq = lane >> 4;

    // XCD-aware bijective swizzle (gridDim.x % 8 == 0)
    const int bid = blockIdx.x;
    const int cpx = (int)gridDim.x >> 3;
    const int wg = (bid & 7) * cpx + (bid >> 3);
    const int m0 = (wg >> 3) * 256;           // 8 n-tiles (N = 2048)
    const int n0 = (wg & 7) * 256;

    const ushort* Ag = A + (size_t)blockIdx.z * astride + (size_t)m0 * lda;
    const ushort* Bg = Bt + (size_t)blockIdx.z * bstride + (size_t)n0 * ldb;
    const int NT = Kdim >> 6;                 // even, >= 2

    // per-thread invariant LDS read offsets (swizzle: row&7 == fr&7)
    const int aoff = wr * 16384 + fr * 128;
    const int boff = wc * 8192 + fr * 128;
    const int xo = (fr & 7) << 4;
    const int cp0 = (fq * 16) ^ xo;           // k-sub 0
    const int cp1 = (64 + fq * 16) ^ xo;      // k-sub 1

    char* buf0 = lds;            // even tiles
    char* buf1 = lds + 65536;    // odd tiles
    const char* Ab0 = buf0 + aoff;
    const char* Bb0 = buf0 + 32768 + boff;
    const char* Ab1 = buf1 + aoff;
    const char* Bb1 = buf1 + 32768 + boff;

    f32x4 acc[8][4];
#pragma unroll
    for (int i = 0; i < 8; i++)
#pragma unroll
        for (int j = 0; j < 4; j++) acc[i][j] = {0.f, 0.f, 0.f, 0.f};

    s16x8 afX[4][2], afY[4][2], bf01[2][2], bf23[2][2];

    // ---- prologue: T0 fully; T1 = {A-lo, B-lo, B-hi}; vmcnt(6) drains T0 ----
    {
        stage_half(buf0,         Ag, lda, 0, tid);
        stage_half(buf0,         Ag, lda, 1, tid);
        stage_half(buf0 + 32768, Bg, ldb, 0, tid);
        stage_half(buf0 + 32768, Bg, ldb, 1, tid);
        stage_half(buf1,         Ag + 64, lda, 0, tid);
        stage_half(buf1 + 32768, Bg + 64, ldb, 0, tid);
        stage_half(buf1 + 32768, Bg + 64, ldb, 1, tid);
        __builtin_amdgcn_sched_barrier(0);
        asm volatile("s_waitcnt vmcnt(6)" ::: "memory");
        __builtin_amdgcn_s_barrier();
    }

    const int NI = NT >> 1;
    for (int j = 0; j < NI; ++j) {
        const int e = 2 * j;
        const bool sE2 = (e + 2 < NT);        // tile T0+2 staged at P2..P5
        const bool sO2 = (e + 3 < NT);        // tile T1+2 staged at P6/P7
        const ushort* AgO  = Ag + (size_t)(e + 1) * 64;   // T1
        const ushort* AgE2 = Ag + (size_t)(e + 2) * 64;
        const ushort* BgE2 = Bg + (size_t)(e + 2) * 64;
        const ushort* AgO2 = Ag + (size_t)(e + 3) * 64;
        const ushort* BgO2 = Bg + (size_t)(e + 3) * 64;

        // ===== P0: stage A-hi(T1); reads afX+bf01 [12]; lgkm(8); bar; Q0 =====
        stage_half(buf1, AgO, lda, 1, tid);
#pragma unroll
        for (int m = 0; m < 4; m++) {
            afX[m][0] = ldfrag(Ab0 + m * 2048 + cp0);
            afX[m][1] = ldfrag(Ab0 + m * 2048 + cp1);
        }
#pragma unroll
        for (int n = 0; n < 2; n++) {
            bf01[n][0] = ldfrag(Bb0 + n * 2048 + cp0);
            bf01[n][1] = ldfrag(Bb0 + n * 2048 + cp1);
        }
        __builtin_amdgcn_sched_barrier(0);
        asm volatile("s_waitcnt lgkmcnt(8)" ::: "memory");
        __builtin_amdgcn_s_barrier();
        asm volatile("s_waitcnt lgkmcnt(0)" ::: "memory");
        __builtin_amdgcn_sched_barrier(0);
        __builtin_amdgcn_s_setprio(1);
#pragma unroll
        for (int k = 0; k < 2; k++)
#pragma unroll
            for (int m = 0; m < 4; m++)
#pragma unroll
                for (int n = 0; n < 2; n++) MFMA_BF16(acc[m][n], afX[m][k], bf01[n][k]);
        __builtin_amdgcn_s_setprio(0);
        __builtin_amdgcn_s_barrier();

        // ===== P1: reads bf23 [4]; bar; Q1 =====
#pragma unroll
        for (int n = 0; n < 2; n++) {
            bf23[n][0] = ldfrag(Bb0 + (n + 2) * 2048 + cp0);
            bf23[n][1] = ldfrag(Bb0 + (n + 2) * 2048 + cp1);
        }
        __builtin_amdgcn_sched_barrier(0);
        __builtin_amdgcn_s_barrier();
        asm volatile("s_waitcnt lgkmcnt(0)" ::: "memory");
        __builtin_amdgcn_sched_barrier(0);
        __builtin_amdgcn_s_setprio(1);
#pragma unroll
        for (int k = 0; k < 2; k++)
#pragma unroll
            for (int m = 0; m < 4; m++)
#pragma unroll
                for (int n = 0; n < 2; n++) MFMA_BF16(acc[m][n + 2], afX[m][k], bf23[n][k]);
        __builtin_amdgcn_s_setprio(0);
        __builtin_amdgcn_s_barrier();

        // ===== P2: stage B-lo(T0+2) (buf0-B free after P1); reads afY [8]; Q2 =====
        if (sE2) stage_half(buf0 + 32768, BgE2, ldb, 0, tid);
#pragma unroll
        for (int m = 0; m < 4; m++) {
            afY[m][0] = ldfrag(Ab0 + (m + 4) * 2048 + cp0);
            afY[m][1] = ldfrag(Ab0 + (m + 4) * 2048 + cp1);
        }
        __builtin_amdgcn_sched_barrier(0);
        __builtin_amdgcn_s_barrier();
        asm volatile("s_waitcnt lgkmcnt(0)" ::: "memory");
        __builtin_amdgcn_sched_barrier(0);
        __builtin_amdgcn_s_setprio(1);
#pragma unroll
        for (int k = 0; k < 2; k++)
#pragma unroll
            for (int m = 0; m < 4; m++)
#pragma unroll
                for (int n = 0; n < 2; n++) MFMA_BF16(acc[m + 4][n], afY[m][k], bf01[n][k]);
        __builtin_amdgcn_s_setprio(0);
        __builtin_amdgcn_s_barrier();

        // ===== P3: stage B-hi(T0+2); Q3; vmcnt(4) -> T1 landed; bar =====
        if (sE2) stage_half(buf0 + 32768, BgE2, ldb, 1, tid);
        __builtin_amdgcn_sched_barrier(0);
        __builtin_amdgcn_s_setprio(1);
#pragma unroll
        for (int k = 0; k < 2; k++)
#pragma unroll
            for (int m = 0; m < 4; m++)
#pragma unroll
                for (int n = 0; n < 2; n++) MFMA_BF16(acc[m + 4][n + 2], afY[m][k], bf23[n][k]);
        __builtin_amdgcn_s_setprio(0);
        __builtin_amdgcn_sched_barrier(0);
        if (sE2) asm volatile("s_waitcnt vmcnt(4)" ::: "memory");
        else     asm volatile("s_waitcnt vmcnt(0)" ::: "memory");
        __builtin_amdgcn_s_barrier();

        // ===== P4: stage A-lo(T0+2) (buf0-A free after P2); reads afX(T1)+bf01(T1) [12] =====
        if (sE2) stage_half(buf0, AgE2, lda, 0, tid);
#pragma unroll
        for (int m = 0; m < 4; m++) {
            afX[m][0] = ldfrag(Ab1 + m * 2048 + cp0);
            afX[m][1] = ldfrag(Ab1 + m * 2048 + cp1);
        }
#pragma unroll
        for (int n = 0; n < 2; n++) {
            bf01[n][0] = ldfrag(Bb1 + n * 2048 + cp0);
            bf01[n][1] = ldfrag(Bb1 + n * 2048 + cp1);
        }
        __builtin_amdgcn_sched_barrier(0);
        asm volatile("s_waitcnt lgkmcnt(8)" ::: "memory");
        __builtin_amdgcn_s_barrier();
        asm volatile("s_waitcnt lgkmcnt(0)" ::: "memory");
        __builtin_amdgcn_sched_barrier(0);
        __builtin_amdgcn_s_setprio(1);
#pragma unroll
        for (int k = 0; k < 2; k++)
#pragma unroll
            for (int m = 0; m < 4; m++)
#pragma unroll
                for (int n = 0; n < 2; n++) MFMA_BF16(acc[m][n], afX[m][k], bf01[n][k]);
        __builtin_amdgcn_s_setprio(0);
        __builtin_amdgcn_s_barrier();

        // ===== P5: stage A-hi(T0+2); reads bf23(T1) [4]; Q1 =====
        if (sE2) stage_half(buf0, AgE2, lda, 1, tid);
#pragma unroll
        for (int n = 0; n < 2; n++) {
            bf23[n][0] = ldfrag(Bb1 + (n + 2) * 2048 + cp0);
            bf23[n][1] = ldfrag(Bb1 + (n + 2) * 2048 + cp1);
        }
        __builtin_amdgcn_sched_barrier(0);
        __builtin_amdgcn_s_barrier();
        asm volatile("s_waitcnt lgkmcnt(0)" ::: "memory");
        __builtin_amdgcn_sched_barrier(0);
        __builtin_amdgcn_s_setprio(1);
#pragma unroll
        for (int k = 0; k < 2; k++)
#pragma unroll
            for (int m = 0; m < 4; m++)
#pragma unroll
                for (int n = 0; n < 2; n++) MFMA_BF16(acc[m][n + 2], afX[m][k], bf23[n][k]);
        __builtin_amdgcn_s_setprio(0);
        __builtin_amdgcn_s_barrier();

        // ===== P6: stage B-lo(T1+2) (buf1-B free after P5); reads afY(T1) [8]; Q2 =====
        if (sO2) stage_half(buf1 + 32768, BgO2, ldb, 0, tid);
#pragma unroll
        for (int m = 0; m < 4; m++) {
            afY[m][0] = ldfrag(Ab1 + (m + 4) * 2048 + cp0);
            afY[m][1] = ldfrag(Ab1 + (m + 4) * 2048 + cp1);
        }
        __builtin_amdgcn_sched_barrier(0);
        __builtin_amdgcn_s_barrier();
        asm volatile("s_waitcnt lgkmcnt(0)" ::: "memory");
        __builtin_amdgcn_sched_barrier(0);
        __builtin_amdgcn_s_setprio(1);
#pragma unroll
        for (int k = 0; k < 2; k++)
#pragma unroll
            for (int m = 0; m < 4; m++)
#pragma unroll
                for (int n = 0; n < 2; n++) MFMA_BF16(acc[m + 4][n], afY[m][k], bf01[n][k]);
        __builtin_amdgcn_s_setprio(0);
        __builtin_amdgcn_s_barrier();

        // ===== P7: stage B-hi(T1+2) + A-lo(T1+2) (buf1-A free after P6); Q3; vmcnt(6) =====
        if (sO2) {
            stage_half(buf1 + 32768, BgO2, ldb, 1, tid);
            stage_half(buf1, AgO2, lda, 0, tid);
        }
        __builtin_amdgcn_sched_barrier(0);
        __builtin_amdgcn_s_setprio(1);
#pragma unroll
        for (int k = 0; k < 2; k++)
#pragma unroll
            for (int m = 0; m < 4; m++)
#pragma unroll
                for (int n = 0; n < 2; n++) MFMA_BF16(acc[m + 4][n + 2], afY[m][k], bf23[n][k]);
        __builtin_amdgcn_s_setprio(0);
        __builtin_amdgcn_sched_barrier(0);
        if (sO2)      asm volatile("s_waitcnt vmcnt(6)" ::: "memory");  // T0+2 landed
        else if (sE2) asm volatile("s_waitcnt vmcnt(4)" ::: "memory");
        else          asm volatile("s_waitcnt vmcnt(0)" ::: "memory");
        __builtin_amdgcn_s_barrier();
    }

    if (MODE == 2) {
        float* C = (float*)Cv + (size_t)blockIdx.z * cstride;
#pragma unroll
        for (int mi = 0; mi < 8; mi++)
#pragma unroll
            for (int ni = 0; ni < 4; ni++)
#pragma unroll
                for (int r = 0; r < 4; r++) {
                    const int row = m0 + wr * 128 + mi * 16 + fq * 4 + r;
                    const int col = n0 + wc * 64 + ni * 16 + fr;
                    const float alibi = 1.0f / (float)(Tt - row);
                    C[(size_t)row * ldc + col] =
                        acc[mi][ni][r] + alibi * S[col] + bias[col];
                }
    } else {
        ushort* C = (ushort*)Cv + (size_t)blockIdx.z * cstride;
#pragma unroll
        for (int mi = 0; mi < 8; mi++)
#pragma unroll
            for (int ni = 0; ni < 4; ni++)
#pragma unroll
                for (int r = 0; r < 4; r++) {
                    const int row = m0 + wr * 128 + mi * 16 + fq * 4 + r;
                    const int col = n0 + wc * 64 + ni * 16 + fr;
                    C[(size_t)row * ldc + col] = f2bf(acc[mi][ni][r]);
                }
    }
}

// ---------------- 128x128 GEMM ----------------
// MODE 3: scores GEMM, z = s*64 + bh, split-K=4 over d; C fp32 -> part.
// MODE 4: Mstack builder, z = b*16 + h: C[n][h*128+g] = sum_f Wt_p[n][hf] wtsT[g][f].

template <int MODE>
__global__ __launch_bounds__(256, 2) void gemm_kernel(
        const ushort* __restrict__ A, const ushort* __restrict__ Bt,
        void* __restrict__ Cv,
        int Kdim, int lda, int ldb, int ldc) {
    __shared__ ushort lsA[128 * 32];
    __shared__ ushort lsB[128 * 32];

    const int tid = threadIdx.x;
    const int w = tid >> 6, lane = tid & 63;
    const int m0 = blockIdx.y * 128;
    const int n0 = blockIdx.x * 128;

    const ushort* Ab = A;
    const ushort* Bb = Bt;
    size_t coff = 0;
    if (MODE == 3) {
        const int z = blockIdx.z, s = z >> 6, bh = z & 63;
        const int b = bh >> 4, h = bh & 15;
        Ab += (size_t)h * 128 * Dd + (size_t)s * 512;
        Bb += (size_t)b * ((size_t)Dd * Dd) + (size_t)h * 128 * Dd + (size_t)s * 512;
        coff = (size_t)s * (64 * 16384) + (size_t)bh * 16384;
    }
    if (MODE == 4) {
        const int z = blockIdx.z, b = z >> 4, h = z & 15;
        Ab += (size_t)h * 128;                    // k-offset into Wt_p
        Bb += (size_t)z * 16384;                  // wtsT block [g][f]
        coff = (size_t)b * ((size_t)Dd * Dd) + (size_t)h * 128;
    }

    const int sr = lane >> 2;
    const int sc = (lane & 3) * 8;
    const int c0 = w, c1 = w + 4;
    const int rA0 = c0 * 16 + sr, rA1 = c1 * 16 + sr;

    const int fr = lane & 15, fq = lane >> 4;
    const int wr = (w >> 1) * 64, wc = (w & 1) * 64;

    f32x4 acc[4][4];
#pragma unroll
    for (int i = 0; i < 4; i++)
#pragma unroll
        for (int j = 0; j < 4; j++) acc[i][j] = {0.f, 0.f, 0.f, 0.f};

    for (int kt = 0; kt < Kdim; kt += 32) {
        gload16(Ab + (size_t)(m0 + rA0) * lda + kt + sc, lsA + c0 * 512);
        gload16(Ab + (size_t)(m0 + rA1) * lda + kt + sc, lsA + c1 * 512);
        gload16(Bb + (size_t)(n0 + rA0) * ldb + kt + sc, lsB + c0 * 512);
        gload16(Bb + (size_t)(n0 + rA1) * ldb + kt + sc, lsB + c1 * 512);
        __syncthreads();

        s16x8 afrag[4], bfrag[4];
#pragma unroll
        for (int i = 0; i < 4; i++)
            afrag[i] = *(const s16x8*)(lsA + (wr + i * 16 + fr) * 32 + fq * 8);
#pragma unroll
        for (int j = 0; j < 4; j++)
            bfrag[j] = *(const s16x8*)(lsB + (wc + j * 16 + fr) * 32 + fq * 8);
#pragma unroll
        for (int i = 0; i < 4; i++)
#pragma unroll
            for (int j = 0; j < 4; j++)
                MFMA_BF16(acc[i][j], afrag[i], bfrag[j]);
        __syncthreads();
    }

    if (MODE == 3) {
        float* C = (float*)Cv + coff;
#pragma unroll
        for (int i = 0; i < 4; i++)
#pragma unroll
            for (int j = 0; j < 4; j++)
#pragma unroll
                for (int r = 0; r < 4; r++) {
                    const int row = m0 + wr + i * 16 + fq * 4 + r;
                    const int col = n0 + wc + j * 16 + fr;
                    C[(size_t)row * ldc + col] = acc[i][j][r];
                }
    } else {
        ushort* C = (ushort*)Cv + coff;
#pragma unroll
        for (int i = 0; i < 4; i++)
#pragma unroll
            for (int j = 0; j < 4; j++)
#pragma unroll
                for (int r = 0; r < 4; r++) {
                    const int row = m0 + wr + i * 16 + fq * 4 + r;
                    const int col = n0 + wc + j * 16 + fr;
                    C[(size_t)row * ldc + col] = f2bf(acc[i][j][r]);
                }
    }
}

// ---------------- softmax over g -> TRANSPOSED weights wtsT[bh][g][f] bf16 ----------------

__global__ __launch_bounds__(256) void softmax_kernel(const float* __restrict__ part,
                                                      ushort* __restrict__ wtsT) {
    const int tid = threadIdx.x;
    const int wv = tid >> 6, lane = tid & 63;
    const int row = blockIdx.x * 4 + wv;          // row = bh*128 + f
    const float* p = part + (size_t)row * 128 + lane * 2;
    float v0 = 0.f, v1 = 0.f;
#pragma unroll
    for (int s = 0; s < 4; s++) {
        const float2 t = *(const float2*)(p + (size_t)s * 1048576);
        v0 += t.x; v1 += t.y;
    }
    const float sc = 0.088388347648318447f;  // 1/sqrt(128)
    v0 *= sc; v1 *= sc;
    float m = fmaxf(v0, v1);
#pragma unroll
    for (int off = 32; off > 0; off >>= 1) m = fmaxf(m, __shfl_xor(m, off));
    const float e0 = __expf(v0 - m), e1 = __expf(v1 - m);
    float smv = e0 + e1;
#pragma unroll
    for (int off = 32; off > 0; off >>= 1) smv += __shfl_xor(smv, off);
    const float inv = 1.0f / smv;
    const int bh = row >> 7, f = row & 127;
    ushort* o = wtsT + (size_t)bh * 16384 + (size_t)(lane * 2) * 128 + f;
    o[0]   = f2bf(e0 * inv);
    o[128] = f2bf(e1 * inv);
}

// ---------------- launch ----------------

extern "C" void kernel_launch(void* const* d_in, const int* in_sizes, int n_in,
                              void* d_out, int out_size, void* d_ws, size_t ws_size,
                              hipStream_t stream) {
    const float* x  = (const float*)d_in[0];
    const float* Wq = (const float*)d_in[1];
    const float* Wk = (const float*)d_in[2];
    const float* Wv = (const float*)d_in[3];
    const float* Wp = (const float*)d_in[4];
    const float* bp = (const float*)d_in[5];
    float* out = (float*)d_out;
    char* ws = (char*)d_ws;

    // ws (MB): xb 0-32 | xT/Mt 32-64 | Wt 64-96 | G/part/wtsT 96-128 | H 128-160
    //          | v 160-192 | S 194 (outside all live regions)
    ushort* xb   = (ushort*)(ws);
    ushort* xT   = (ushort*)(ws + (32ull << 20));
    ushort* Wt   = (ushort*)(ws + (64ull << 20));
    ushort* G    = (ushort*)(ws + (96ull << 20));
    ushort* Hb   = (ushort*)(ws + (128ull << 20));
    ushort* v    = (ushort*)(ws + (160ull << 20));
    float*  part = (float*) (ws + (96ull << 20));   // overlays G[b0,b1] (dead after H)
    ushort* wtsT = (ushort*)(ws + (112ull << 20));  // overlays G[b2] (dead after H)
    float*  S    = (float*) (ws + (194ull << 20));  // safe: beyond v region
    ushort* Mt   = xT;                              // xT dead after G

    const size_t WSZ = (size_t)Dd * Dd;  // 4M elements
    const size_t TD  = (size_t)Tt * Dd;

    static_cast<void>(hipFuncSetAttribute((const void*)gemm256_kernel<0>,
        hipFuncAttributeMaxDynamicSharedMemorySize, 131072));
    static_cast<void>(hipFuncSetAttribute((const void*)gemm256_kernel<2>,
        hipFuncAttributeMaxDynamicSharedMemorySize, 131072));

    static_cast<void>(hipMemsetAsync(S, 0, Dd * sizeof(float), stream));
    convxT_kernel<<<dim3(32, 32, 4), 256, 0, stream>>>(x, xb, xT);
    transw_kernel<<<dim3(32, 32, 4), 256, 0, stream>>>(Wq, Wk, Wv, Wp, Wt, S);

    // G_b = X_b^T X_b : A = Bt = xT_b [d][t]
    gemm256_kernel<0><<<dim3(64, 1, 4), 512, 131072, stream>>>(
        xT, xT, G, nullptr, nullptr, 2048, 2048, 2048, 2048, WSZ, WSZ, WSZ);

    // H_b = Wk^T G_b : A = Wt_k, Bt = G_b
    gemm256_kernel<0><<<dim3(64, 1, 4), 512, 131072, stream>>>(
        Wt + WSZ, G, Hb, nullptr, nullptr, 2048, 2048, 2048, 2048, 0, WSZ, WSZ);

    // v = X Wv
    gemm256_kernel<0><<<dim3(256, 1, 1), 512, 131072, stream>>>(
        xb, Wt + 2 * WSZ, v, nullptr, nullptr, 2048, 2048, 2048, 2048, 0, 0, 0);

    // scores: part[s][bh][f][g] = sum_{d in slice s} Wt_q[hf][d] * H_b[hg][d]
    gemm_kernel<3><<<dim3(1, 1, 256), 256, 0, stream>>>(
        Wt, Hb, part, 512, 2048, 2048, 128);

    softmax_kernel<<<2048, 256, 0, stream>>>(part, wtsT);

    // Mt[b][n][h*128+g] = sum_f Wt_p[n][hf] * wtsT[bh][g][f]
    gemm_kernel<4><<<dim3(1, 16, 64), 256, 0, stream>>>(
        Wt + 3 * WSZ, wtsT, Mt, 128, 2048, 128, 2048);

    // out_b = v_b @ Mt_b^T + alibi (x) S + bp   (fp32 out)
    gemm256_kernel<2><<<dim3(64, 1, 4), 512, 131072, stream>>>(
        v, Mt, out, bp, S, 2048, 2048, 2048, 2048, TD, WSZ, TD);
}